// Round 2
// baseline (1001.770 us; speedup 1.0000x reference)
//
#include <hip/hip_runtime.h>

#define DIN  128
#define DHID 16
#define NCLS 40

// ---------------- K1: X1 = H @ W1   [n,128]@[128,16] ----------------
__global__ __launch_bounds__(256) void k1_gemm_hw1(
    const float* __restrict__ H, const float* __restrict__ W1,
    float* __restrict__ X1, int n)
{
    __shared__ __align__(16) float w[DIN * DHID];   // 8 KB
    for (int i = threadIdx.x; i < DIN * DHID; i += 256) w[i] = W1[i];
    __syncthreads();
    int r = blockIdx.x * 256 + threadIdx.x;
    if (r >= n) return;
    const float4* hrow = (const float4*)(H + (size_t)r * DIN);
    float acc[DHID];
#pragma unroll
    for (int j = 0; j < DHID; ++j) acc[j] = 0.f;
#pragma unroll 4
    for (int k4 = 0; k4 < DIN / 4; ++k4) {
        float4 h = hrow[k4];
        float hh[4] = {h.x, h.y, h.z, h.w};
#pragma unroll
        for (int kk = 0; kk < 4; ++kk) {
#pragma unroll
            for (int j4 = 0; j4 < DHID / 4; ++j4) {
                float4 wv = *(const float4*)&w[(4 * k4 + kk) * DHID + 4 * j4];
                acc[4 * j4 + 0] += hh[kk] * wv.x;
                acc[4 * j4 + 1] += hh[kk] * wv.y;
                acc[4 * j4 + 2] += hh[kk] * wv.z;
                acc[4 * j4 + 3] += hh[kk] * wv.w;
            }
        }
    }
    float4* o = (float4*)(X1 + (size_t)r * DHID);
#pragma unroll
    for (int q = 0; q < DHID / 4; ++q)
        o[q] = make_float4(acc[4*q], acc[4*q+1], acc[4*q+2], acc[4*q+3]);
}

// ---------------- CSR build ----------------
__global__ __launch_bounds__(256) void k_hist(
    const int* __restrict__ rows, unsigned* __restrict__ cnt, int nnz)
{
    for (int e = blockIdx.x * 256 + threadIdx.x; e < nnz; e += gridDim.x * 256)
        atomicAdd(&cnt[rows[e]], 1u);
}

// block-local exclusive scan over 1024 elements/block
__global__ __launch_bounds__(256) void k_scan1(
    const unsigned* __restrict__ cnt, unsigned* __restrict__ rs,
    unsigned* __restrict__ bsum, int n)
{
    __shared__ unsigned s[256];
    int tid = threadIdx.x;
    int idx = blockIdx.x * 1024 + tid * 4;
    unsigned v[4], tsum = 0;
#pragma unroll
    for (int q = 0; q < 4; ++q) {
        v[q] = (idx + q < n) ? cnt[idx + q] : 0u;
        tsum += v[q];
    }
    s[tid] = tsum; __syncthreads();
    for (int off = 1; off < 256; off <<= 1) {
        unsigned t = (tid >= off) ? s[tid - off] : 0u;
        __syncthreads();
        s[tid] += t;
        __syncthreads();
    }
    unsigned run = s[tid] - tsum;  // exclusive
#pragma unroll
    for (int q = 0; q < 4; ++q) {
        if (idx + q < n) rs[idx + q] = run;
        run += v[q];
    }
    if (tid == 255) bsum[blockIdx.x] = s[255];
}

__global__ __launch_bounds__(256) void k_scan2(unsigned* __restrict__ bsum, int nb)
{
    __shared__ unsigned s[256];
    int tid = threadIdx.x;
    unsigned v = (tid < nb) ? bsum[tid] : 0u;
    s[tid] = v; __syncthreads();
    for (int off = 1; off < 256; off <<= 1) {
        unsigned t = (tid >= off) ? s[tid - off] : 0u;
        __syncthreads();
        s[tid] += t;
        __syncthreads();
    }
    if (tid < nb) bsum[tid] = s[tid] - v;  // exclusive
}

__global__ __launch_bounds__(256) void k_scan3(
    unsigned* __restrict__ rs, unsigned* __restrict__ cur,
    const unsigned* __restrict__ bsum, int n, unsigned nnz)
{
    int i = blockIdx.x * 256 + threadIdx.x;
    if (i < n) {
        unsigned v = rs[i] + bsum[i >> 10];
        rs[i] = v;
        cur[i] = v;
    } else if (i == n) {
        rs[n] = nnz;
    }
}

__global__ __launch_bounds__(256) void k_reorder(
    const int* __restrict__ rows, const int* __restrict__ cols,
    const float* __restrict__ vals, unsigned* __restrict__ cur,
    int2* __restrict__ colv, int nnz)
{
    for (int e = blockIdx.x * 256 + threadIdx.x; e < nnz; e += gridDim.x * 256) {
        int r = rows[e];
        unsigned p = atomicAdd(&cur[r], 1u);
        colv[p] = make_int2(cols[e], __float_as_int(vals[e]));
    }
}

// ---------------- CSR SpMM (gather): one wave per row ----------------
// lanes: eg = lane>>4 (edge group 0..3), j = lane&15 (feature)
__global__ __launch_bounds__(256) void k_spmm(
    const unsigned* __restrict__ rs, const int2* __restrict__ colv,
    const float* __restrict__ src, const float* __restrict__ bias,
    int do_relu, float* __restrict__ dst, int n)
{
    int w = blockIdx.x * 4 + (threadIdx.x >> 6);
    if (w >= n) return;
    int lane = threadIdx.x & 63;
    int eg = lane >> 4, j = lane & 15;
    unsigned s0 = rs[w], s1 = rs[w + 1];
    float bj = do_relu ? bias[j] : 0.f;
    float acc = 0.f;
    for (unsigned i = s0 + eg; i < s1; i += 4) {
        int2 cv = colv[i];
        float x = src[(size_t)cv.x * DHID + j];
        if (do_relu) x = fmaxf(x + bj, 0.f);
        acc += x * __int_as_float(cv.y);
    }
    acc += __shfl_xor(acc, 16, 64);
    acc += __shfl_xor(acc, 32, 64);
    if (eg == 0) dst[(size_t)w * DHID + j] = acc;
}

// ---------------- fallback scatter (if ws too small) ----------------
__global__ __launch_bounds__(256) void k2_scatter16(
    const int* __restrict__ rows, const int* __restrict__ cols,
    const float* __restrict__ vals, const float* __restrict__ src,
    const float* __restrict__ bias, int do_relu,
    float* __restrict__ dst, int nnz)
{
    unsigned int tid = blockIdx.x * 256u + threadIdx.x;
    int e = (int)(tid >> 4);
    int j = (int)(tid & 15u);
    if (e >= nnz) return;
    int c = cols[e];
    int r = rows[e];
    float x = src[(size_t)c * DHID + j];
    if (do_relu) x = fmaxf(x + bias[j], 0.f);
    atomicAdd(&dst[(size_t)r * DHID + j], x * vals[e]);
}

// ---------------- K4: out = log_softmax(relu(T @ W2 + b2)) ----------------
__global__ __launch_bounds__(256) void k4_final(
    const float* __restrict__ T, const float* __restrict__ W2,
    const float* __restrict__ b2, float* __restrict__ out, int n)
{
    __shared__ __align__(16) float w[DHID * NCLS];
    __shared__ float bb[NCLS];
    for (int i = threadIdx.x; i < DHID * NCLS; i += 256) w[i] = W2[i];
    if (threadIdx.x < NCLS) bb[threadIdx.x] = b2[threadIdx.x];
    __syncthreads();
    int r = blockIdx.x * 256 + threadIdx.x;
    if (r >= n) return;
    float t[DHID];
    const float4* trow = (const float4*)(T + (size_t)r * DHID);
#pragma unroll
    for (int q = 0; q < DHID / 4; ++q) {
        float4 v = trow[q];
        t[4*q+0] = v.x; t[4*q+1] = v.y; t[4*q+2] = v.z; t[4*q+3] = v.w;
    }
    float o[NCLS];
#pragma unroll
    for (int j = 0; j < NCLS; ++j) o[j] = bb[j];
#pragma unroll 4
    for (int k = 0; k < DHID; ++k) {
        float tk = t[k];
#pragma unroll
        for (int j4 = 0; j4 < NCLS / 4; ++j4) {
            float4 wv = *(const float4*)&w[k * NCLS + 4 * j4];
            o[4*j4+0] += tk * wv.x;
            o[4*j4+1] += tk * wv.y;
            o[4*j4+2] += tk * wv.z;
            o[4*j4+3] += tk * wv.w;
        }
    }
    float m = 0.f;
#pragma unroll
    for (int j = 0; j < NCLS; ++j) {
        o[j] = fmaxf(o[j], 0.f);
        m = fmaxf(m, o[j]);
    }
    float s = 0.f;
#pragma unroll
    for (int j = 0; j < NCLS; ++j) s += __expf(o[j] - m);
    float ls = m + __logf(s);
    float4* orow = (float4*)(out + (size_t)r * NCLS);
#pragma unroll
    for (int j4 = 0; j4 < NCLS / 4; ++j4)
        orow[j4] = make_float4(o[4*j4+0]-ls, o[4*j4+1]-ls, o[4*j4+2]-ls, o[4*j4+3]-ls);
}

extern "C" void kernel_launch(void* const* d_in, const int* in_sizes, int n_in,
                              void* d_out, int out_size, void* d_ws, size_t ws_size,
                              hipStream_t stream)
{
    const float* H    = (const float*)d_in[0];
    const int*   rows = (const int*)d_in[1];
    const int*   cols = (const int*)d_in[2];
    const float* vals = (const float*)d_in[3];
    const float* W1   = (const float*)d_in[4];
    const float* b1   = (const float*)d_in[5];
    const float* W2   = (const float*)d_in[6];
    const float* b2   = (const float*)d_in[7];
    float* out = (float*)d_out;

    int n   = in_sizes[0] / DIN;   // 200000
    int nnz = in_sizes[1];         // 6,400,000

    // ---- workspace layout ----
    float* A = (float*)d_ws;                    // n*16 f32 : X1, then T
    float* B = A + (size_t)n * DHID;            // n*16 f32 : S1
    unsigned* rs   = (unsigned*)(B + (size_t)n * DHID);  // n+1
    unsigned* cur  = rs + (n + 1);                        // n
    unsigned* bsum = cur + n;                             // 256
    size_t head = (size_t)((char*)(bsum + 256) - (char*)d_ws);
    head = (head + 15) & ~(size_t)15;
    int2* colv = (int2*)((char*)d_ws + head);             // nnz int2
    size_t needed = head + (size_t)nnz * sizeof(int2);

    int rb = (n + 255) / 256;

    // X1 = H @ W1
    k1_gemm_hw1<<<rb, 256, 0, stream>>>(H, W1, A, n);

    if (needed <= ws_size) {
        // ---- CSR build (counting sort by destination row) ----
        hipMemsetAsync(cur, 0, (size_t)n * sizeof(unsigned), stream);   // cnt
        k_hist<<<2048, 256, 0, stream>>>(rows, cur, nnz);
        int nb = (n + 1023) / 1024;  // 196 (<=256 required by k_scan2)
        k_scan1<<<nb, 256, 0, stream>>>(cur, rs, bsum, n);
        k_scan2<<<1, 256, 0, stream>>>(bsum, nb);
        k_scan3<<<(n + 256) / 256 + 1, 256, 0, stream>>>(rs, cur, bsum, n, (unsigned)nnz);
        k_reorder<<<2048, 256, 0, stream>>>(rows, cols, vals, cur, colv, nnz);

        int sbw = (n + 3) / 4;  // 4 waves (rows) per 256-block
        // S1 = A_sp @ X1
        k_spmm<<<sbw, 256, 0, stream>>>(rs, colv, A, nullptr, 0, B, n);
        // T = A_sp @ relu(S1 + b1)
        k_spmm<<<sbw, 256, 0, stream>>>(rs, colv, B, b1, 1, A, n);
    } else {
        // ---- fallback: atomic scatter path ----
        unsigned int sb = (unsigned int)(((long long)nnz * DHID + 255) / 256);
        hipMemsetAsync(B, 0, (size_t)n * DHID * sizeof(float), stream);
        k2_scatter16<<<sb, 256, 0, stream>>>(rows, cols, vals, A, nullptr, 0, B, nnz);
        hipMemsetAsync(A, 0, (size_t)n * DHID * sizeof(float), stream);
        k2_scatter16<<<sb, 256, 0, stream>>>(rows, cols, vals, B, b1, 1, A, nnz);
    }

    // out = log_softmax(relu(T @ W2 + b2))
    k4_final<<<rb, 256, 0, stream>>>(A, W2, b2, out, n);
}